// Round 4
// baseline (228.541 us; speedup 1.0000x reference)
//
#include <hip/hip_runtime.h>

#define LSEQ 512
#define RCA 3.8f

// Affine 4x4 with implicit bottom row (0,0,0,1), stored as 3x4.
struct Aff { float m[3][4]; };

__device__ __forceinline__ Aff compose(const Aff& A, const Aff& B) {
    Aff C;
#pragma unroll
    for (int i = 0; i < 3; ++i) {
#pragma unroll
        for (int j = 0; j < 4; ++j) {
            float v = A.m[i][0] * B.m[0][j] + A.m[i][1] * B.m[1][j] + A.m[i][2] * B.m[2][j];
            if (j == 3) v += A.m[i][3];
            C.m[i][j] = v;
        }
    }
    return C;
}

__device__ __forceinline__ Aff shflUp(const Aff& a, int d) {
    Aff r;
#pragma unroll
    for (int i = 0; i < 3; ++i)
#pragma unroll
        for (int j = 0; j < 4; ++j)
            r.m[i][j] = __shfl_up(a.m[i][j], d, 64);
    return r;
}

__device__ __forceinline__ Aff makeB(float ca, float sa, float cb, float sb) {
    Aff B;
    B.m[0][0] = ca;  B.m[0][1] = -sa * cb; B.m[0][2] =  sa * sb; B.m[0][3] = RCA * ca;
    B.m[1][0] = sa;  B.m[1][1] =  ca * cb; B.m[1][2] = -ca * sb; B.m[1][3] = RCA * sa;
    B.m[2][0] = 0.f; B.m[2][1] =  sb;      B.m[2][2] =  cb;      B.m[2][3] = 0.f;
    return B;
}

// One block (1 wave of 64) per batch. Lane t owns l = 8t..8t+7.
// Computes Fa[l], Fb[l] (3x4 each, fp32) into F[(b*512+l)*24 + {0..23}].
__global__ __launch_bounds__(64) void scan_kernel(const float* __restrict__ angles,
                                                  float* __restrict__ F) {
    const int b = blockIdx.x;
    const int lane = threadIdx.x;

    const float* ap = angles + (size_t)b * 1024 + lane * 8;
    float4 a0 = *reinterpret_cast<const float4*>(ap);
    float4 a1 = *reinterpret_cast<const float4*>(ap + 4);
    float4 b0 = *reinterpret_cast<const float4*>(ap + 512);
    float4 b1 = *reinterpret_cast<const float4*>(ap + 516);
    float av[8] = {a0.x, a0.y, a0.z, a0.w, a1.x, a1.y, a1.z, a1.w};
    float bv[8] = {b0.x, b0.y, b0.z, b0.w, b1.x, b1.y, b1.z, b1.w};

    float ca[8], sa[8], cb[8], sb[8];
#pragma unroll
    for (int e = 0; e < 8; ++e) {
        sincosf(av[e], &sa[e], &ca[e]);
        sincosf(bv[e], &sb[e], &cb[e]);
    }

    // local chunk product (left-to-right)
    Aff P = makeB(ca[0], sa[0], cb[0], sb[0]);
#pragma unroll
    for (int e = 1; e < 8; ++e) P = compose(P, makeB(ca[e], sa[e], cb[e], sb[e]));

    // inclusive Hillis-Steele scan across 64 lanes
    Aff S = P;
#pragma unroll
    for (int d = 1; d < 64; d <<= 1) {
        Aff o = shflUp(S, d);
        if (lane >= d) S = compose(o, S);
    }
    // exclusive prefix for this lane's chunk
    Aff Mprev = shflUp(S, 1);
    if (lane == 0) {
#pragma unroll
        for (int i = 0; i < 3; ++i)
#pragma unroll
            for (int j = 0; j < 4; ++j)
                Mprev.m[i][j] = (i == j) ? 1.f : 0.f;
    }

#pragma unroll
    for (int e = 0; e < 8; ++e) {
        const int l = lane * 8 + e;
        Aff B = makeB(ca[e], sa[e], cb[e], sb[e]);
        Aff M = compose(Mprev, B);

        // Minv = [R^T | -R^T t]
        float Rt[3][3], ti[3];
#pragma unroll
        for (int i = 0; i < 3; ++i)
#pragma unroll
            for (int j = 0; j < 3; ++j) Rt[i][j] = M.m[j][i];
#pragma unroll
        for (int i = 0; i < 3; ++i)
            ti[i] = -(M.m[0][i] * M.m[0][3] + M.m[1][i] * M.m[1][3] + M.m[2][i] * M.m[2][3]);

        // dB_da: only rows 0,1 nonzero
        float d0[4] = {-sa[e], -ca[e] * cb[e],  ca[e] * sb[e], -RCA * sa[e]};
        float d1[4] = { ca[e], -sa[e] * cb[e],  sa[e] * sb[e],  RCA * ca[e]};
        // dB_db: only cols 1,2 nonzero (rows 0..2)
        float e01 =  sa[e] * sb[e], e02 =  sa[e] * cb[e];
        float e11 = -ca[e] * sb[e], e12 = -ca[e] * cb[e];
        float e21 =  cb[e],         e22 = -sb[e];

        float Ga[3][4], Gb[3][4];
#pragma unroll
        for (int i = 0; i < 3; ++i) {
            float p0 = Mprev.m[i][0], p1 = Mprev.m[i][1], p2 = Mprev.m[i][2];
#pragma unroll
            for (int j = 0; j < 4; ++j) Ga[i][j] = p0 * d0[j] + p1 * d1[j];
            Gb[i][0] = 0.f;
            Gb[i][1] = p0 * e01 + p1 * e11 + p2 * e21;
            Gb[i][2] = p0 * e02 + p1 * e12 + p2 * e22;
            Gb[i][3] = 0.f;
        }

        // F = G @ Minv
        float W[24];
#pragma unroll
        for (int i = 0; i < 3; ++i) {
#pragma unroll
            for (int j = 0; j < 3; ++j) {
                W[i * 4 + j]      = Ga[i][0] * Rt[0][j] + Ga[i][1] * Rt[1][j] + Ga[i][2] * Rt[2][j];
                W[12 + i * 4 + j] = Gb[i][0] * Rt[0][j] + Gb[i][1] * Rt[1][j] + Gb[i][2] * Rt[2][j];
            }
            W[i * 4 + 3]      = Ga[i][0] * ti[0] + Ga[i][1] * ti[1] + Ga[i][2] * ti[2] + Ga[i][3];
            W[12 + i * 4 + 3] = Gb[i][0] * ti[0] + Gb[i][1] * ti[1] + Gb[i][2] * ti[2] + Gb[i][3];
        }

        float4* w4 = reinterpret_cast<float4*>(F + ((size_t)b * LSEQ + l) * 24);
        const float4* s4 = reinterpret_cast<const float4*>(W);
#pragma unroll
        for (int q = 0; q < 6; ++q) w4[q] = s4[q];

        Mprev = M;
    }
}

// grid (512, 32), block 256. Block (l, b) writes out[b, {a,b}, l, 0..512, 0..2] (fp32).
__global__ __launch_bounds__(256) void emit_kernel(const float* __restrict__ F,
                                                   const float* __restrict__ coords,
                                                   const int* __restrict__ lens,
                                                   float* __restrict__ out) {
    const int l = blockIdx.x;
    const int b = blockIdx.y;
    const int tid = threadIdx.x;

    __shared__ float sF[24];
    __shared__ float sC[1539];
    if (tid < 24) sF[tid] = F[((size_t)b * LSEQ + l) * 24 + tid];
    for (int i = tid; i < 1539; i += 256) sC[i] = coords[(size_t)b * 1539 + i];
    __syncthreads();

    const int len = lens[b];
    const bool rowActive = (l < len);
    const size_t baseA = ((size_t)(b * 2) * LSEQ + l) * 1539;
    const size_t baseB = baseA + (size_t)LSEQ * 1539;

    const float f00 = sF[0],  f01 = sF[1],  f02 = sF[2],  f03 = sF[3];
    const float f10 = sF[4],  f11 = sF[5],  f12 = sF[6],  f13 = sF[7];
    const float f20 = sF[8],  f21 = sF[9],  f22 = sF[10], f23 = sF[11];
    const float g00 = sF[12], g01 = sF[13], g02 = sF[14], g03 = sF[15];
    const float g10 = sF[16], g11 = sF[17], g12 = sF[18], g13 = sF[19];
    const float g20 = sF[20], g21 = sF[21], g22 = sF[22], g23 = sF[23];

    for (int m = tid; m < 513; m += 256) {
        const float x = sC[m * 3];
        const float y = sC[m * 3 + 1];
        const float z = sC[m * 3 + 2];
        const bool act = rowActive && (m > l) && (m <= len);
        const float s = act ? 1.f : 0.f;

        float3 va, vb;
        va.x = s * (f00 * x + f01 * y + f02 * z + f03);
        va.y = s * (f10 * x + f11 * y + f12 * z + f13);
        va.z = s * (f20 * x + f21 * y + f22 * z + f23);
        vb.x = s * (g00 * x + g01 * y + g02 * z + g03);
        vb.y = s * (g10 * x + g11 * y + g12 * z + g13);
        vb.z = s * (g20 * x + g21 * y + g22 * z + g23);

        *reinterpret_cast<float3*>(out + baseA + (size_t)m * 3) = va;
        *reinterpret_cast<float3*>(out + baseB + (size_t)m * 3) = vb;
    }
}

extern "C" void kernel_launch(void* const* d_in, const int* in_sizes, int n_in,
                              void* d_out, int out_size, void* d_ws, size_t ws_size,
                              hipStream_t stream) {
    const float* angles = (const float*)d_in[0];   // fp32 (32, 2, 512)
    const float* coords = (const float*)d_in[1];   // fp32 (32, 1539)
    const int*   lens   = (const int*)d_in[2];     // int32 (32,)
    float* out = (float*)d_out;                    // fp32 output (reference dtype)
    float* F = (float*)d_ws;                       // 32*512*24 fp32 = 1.57 MB scratch

    scan_kernel<<<32, 64, 0, stream>>>(angles, F);
    emit_kernel<<<dim3(LSEQ, 32), 256, 0, stream>>>(F, coords, lens, out);
}

// Round 5
// 206.358 us; speedup vs baseline: 1.1075x; 1.1075x over previous
//
#include <hip/hip_runtime.h>

#define LSEQ 512
#define RCA 3.8f

// Affine 4x4 with implicit bottom row (0,0,0,1), stored as 3x4.
struct Aff { float m[3][4]; };

__device__ __forceinline__ Aff compose(const Aff& A, const Aff& B) {
    Aff C;
#pragma unroll
    for (int i = 0; i < 3; ++i) {
#pragma unroll
        for (int j = 0; j < 4; ++j) {
            float v = A.m[i][0] * B.m[0][j] + A.m[i][1] * B.m[1][j] + A.m[i][2] * B.m[2][j];
            if (j == 3) v += A.m[i][3];
            C.m[i][j] = v;
        }
    }
    return C;
}

__device__ __forceinline__ Aff shflUp(const Aff& a, int d) {
    Aff r;
#pragma unroll
    for (int i = 0; i < 3; ++i)
#pragma unroll
        for (int j = 0; j < 4; ++j)
            r.m[i][j] = __shfl_up(a.m[i][j], d, 64);
    return r;
}

__device__ __forceinline__ Aff makeB(float ca, float sa, float cb, float sb) {
    Aff B;
    B.m[0][0] = ca;  B.m[0][1] = -sa * cb; B.m[0][2] =  sa * sb; B.m[0][3] = RCA * ca;
    B.m[1][0] = sa;  B.m[1][1] =  ca * cb; B.m[1][2] = -ca * sb; B.m[1][3] = RCA * sa;
    B.m[2][0] = 0.f; B.m[2][1] =  sb;      B.m[2][2] =  cb;      B.m[2][3] = 0.f;
    return B;
}

// One block (512 threads = 8 waves) per batch. Thread tid owns l = tid.
// Wave-level scan + cross-wave combine. F[(b*512+l)*24 + {0..23}] = {Fa, Fb}.
__global__ __launch_bounds__(512) void scan_kernel(const float* __restrict__ angles,
                                                   float* __restrict__ F) {
    const int b = blockIdx.x;
    const int tid = threadIdx.x;   // = l
    const int lane = tid & 63;
    const int w = tid >> 6;

    __shared__ float sT[8][12];    // per-wave inclusive totals

    const float a  = angles[(size_t)b * 1024 + tid];
    const float be = angles[(size_t)b * 1024 + 512 + tid];
    float sa, ca, sb, cb;
    sincosf(a, &sa, &ca);
    sincosf(be, &sb, &cb);

    // wave-inclusive scan of single matrices
    Aff S = makeB(ca, sa, cb, sb);
#pragma unroll
    for (int d = 1; d < 64; d <<= 1) {
        Aff o = shflUp(S, d);
        if (lane >= d) S = compose(o, S);
    }

    if (lane == 63) {
#pragma unroll
        for (int k = 0; k < 12; ++k) sT[w][k] = S.m[k / 4][k % 4];
    }
    __syncthreads();

    // exclusive cross-wave prefix E_w = T_0 @ ... @ T_{w-1}
    Aff E;
#pragma unroll
    for (int i = 0; i < 3; ++i)
#pragma unroll
        for (int j = 0; j < 4; ++j) E.m[i][j] = (i == j) ? 1.f : 0.f;
    for (int k = 0; k < w; ++k) {
        Aff T;
#pragma unroll
        for (int q = 0; q < 12; ++q) T.m[q / 4][q % 4] = sT[k][q];
        E = compose(E, T);
    }

    const Aff Sp = shflUp(S, 1);
    const Aff M = compose(E, S);                      // inclusive prefix at l
    Aff Mprev;
    if (lane == 0) Mprev = E;
    else           Mprev = compose(E, Sp);            // inclusive prefix at l-1

    // ---- epilogue: Fa/Fb = Mprev @ dB @ Minv ----
    float Rt[3][3], ti[3];
#pragma unroll
    for (int i = 0; i < 3; ++i)
#pragma unroll
        for (int j = 0; j < 3; ++j) Rt[i][j] = M.m[j][i];
#pragma unroll
    for (int i = 0; i < 3; ++i)
        ti[i] = -(M.m[0][i] * M.m[0][3] + M.m[1][i] * M.m[1][3] + M.m[2][i] * M.m[2][3]);

    // dB_da: rows 0,1 nonzero
    float d0[4] = {-sa, -ca * cb,  ca * sb, -RCA * sa};
    float d1[4] = { ca, -sa * cb,  sa * sb,  RCA * ca};
    // dB_db: cols 1,2 nonzero
    float e01 =  sa * sb, e02 =  sa * cb;
    float e11 = -ca * sb, e12 = -ca * cb;
    float e21 =  cb,      e22 = -sb;

    float Ga[3][4], Gb[3][4];
#pragma unroll
    for (int i = 0; i < 3; ++i) {
        float p0 = Mprev.m[i][0], p1 = Mprev.m[i][1], p2 = Mprev.m[i][2];
#pragma unroll
        for (int j = 0; j < 4; ++j) Ga[i][j] = p0 * d0[j] + p1 * d1[j];
        Gb[i][0] = 0.f;
        Gb[i][1] = p0 * e01 + p1 * e11 + p2 * e21;
        Gb[i][2] = p0 * e02 + p1 * e12 + p2 * e22;
        Gb[i][3] = 0.f;
    }

    float W[24];
#pragma unroll
    for (int i = 0; i < 3; ++i) {
#pragma unroll
        for (int j = 0; j < 3; ++j) {
            W[i * 4 + j]      = Ga[i][0] * Rt[0][j] + Ga[i][1] * Rt[1][j] + Ga[i][2] * Rt[2][j];
            W[12 + i * 4 + j] = Gb[i][0] * Rt[0][j] + Gb[i][1] * Rt[1][j] + Gb[i][2] * Rt[2][j];
        }
        W[i * 4 + 3]      = Ga[i][0] * ti[0] + Ga[i][1] * ti[1] + Ga[i][2] * ti[2] + Ga[i][3];
        W[12 + i * 4 + 3] = Gb[i][0] * ti[0] + Gb[i][1] * ti[1] + Gb[i][2] * ti[2] + Gb[i][3];
    }

    float4* w4 = reinterpret_cast<float4*>(F + ((size_t)b * LSEQ + tid) * 24);
    const float4* s4 = reinterpret_cast<const float4*>(W);
#pragma unroll
    for (int q = 0; q < 6; ++q) w4[q] = s4[q];
}

// grid (128, 32), block 256. Block handles l = 4*bx .. 4*bx+3 for batch by.
__global__ __launch_bounds__(256) void emit_kernel(const float* __restrict__ F,
                                                   const float* __restrict__ coords,
                                                   const int* __restrict__ lens,
                                                   float* __restrict__ out) {
    const int b = blockIdx.y;
    const int l0 = blockIdx.x * 4;
    const int tid = threadIdx.x;

    __shared__ float sF[96];
    if (tid < 96) sF[tid] = F[((size_t)b * LSEQ + l0) * 24 + tid];
    __syncthreads();

    const int len = lens[b];
    const float* cp = coords + (size_t)b * 1539;

    // preload coords for m = tid, tid+256, (tid+512 when valid: tid==0)
    const int m0 = tid, m1 = tid + 256, m2 = tid + 512;
    const float cx0 = cp[m0 * 3], cy0 = cp[m0 * 3 + 1], cz0 = cp[m0 * 3 + 2];
    const float cx1 = cp[m1 * 3], cy1 = cp[m1 * 3 + 1], cz1 = cp[m1 * 3 + 2];
    const bool has2 = (m2 < 513);
    float cx2 = 0.f, cy2 = 0.f, cz2 = 0.f;
    if (has2) { cx2 = cp[m2 * 3]; cy2 = cp[m2 * 3 + 1]; cz2 = cp[m2 * 3 + 2]; }

#pragma unroll
    for (int i = 0; i < 4; ++i) {
        const int l = l0 + i;
        const float* f = sF + i * 24;
        const float f00 = f[0],  f01 = f[1],  f02 = f[2],  f03 = f[3];
        const float f10 = f[4],  f11 = f[5],  f12 = f[6],  f13 = f[7];
        const float f20 = f[8],  f21 = f[9],  f22 = f[10], f23 = f[11];
        const float g00 = f[12], g01 = f[13], g02 = f[14], g03 = f[15];
        const float g10 = f[16], g11 = f[17], g12 = f[18], g13 = f[19];
        const float g20 = f[20], g21 = f[21], g22 = f[22], g23 = f[23];

        const size_t baseA = ((size_t)(b * 2) * LSEQ + l) * 1539;
        const size_t baseB = baseA + (size_t)LSEQ * 1539;
        const bool rowActive = (l < len);

        auto emit1 = [&](int m, float x, float y, float z) {
            const float s = (rowActive && (m > l) && (m <= len)) ? 1.f : 0.f;
            float3 va, vb;
            va.x = s * (f00 * x + f01 * y + f02 * z + f03);
            va.y = s * (f10 * x + f11 * y + f12 * z + f13);
            va.z = s * (f20 * x + f21 * y + f22 * z + f23);
            vb.x = s * (g00 * x + g01 * y + g02 * z + g03);
            vb.y = s * (g10 * x + g11 * y + g12 * z + g13);
            vb.z = s * (g20 * x + g21 * y + g22 * z + g23);
            *reinterpret_cast<float3*>(out + baseA + (size_t)m * 3) = va;
            *reinterpret_cast<float3*>(out + baseB + (size_t)m * 3) = vb;
        };

        emit1(m0, cx0, cy0, cz0);
        emit1(m1, cx1, cy1, cz1);
        if (has2) emit1(m2, cx2, cy2, cz2);
    }
}

extern "C" void kernel_launch(void* const* d_in, const int* in_sizes, int n_in,
                              void* d_out, int out_size, void* d_ws, size_t ws_size,
                              hipStream_t stream) {
    const float* angles = (const float*)d_in[0];   // fp32 (32, 2, 512)
    const float* coords = (const float*)d_in[1];   // fp32 (32, 1539)
    const int*   lens   = (const int*)d_in[2];     // int32 (32,)
    float* out = (float*)d_out;                    // fp32 output
    float* F = (float*)d_ws;                       // 32*512*24 fp32 = 1.57 MB scratch

    scan_kernel<<<32, 512, 0, stream>>>(angles, F);
    emit_kernel<<<dim3(128, 32), 256, 0, stream>>>(F, coords, lens, out);
}